// Round 1
// baseline (529.067 us; speedup 1.0000x reference)
//
#include <hip/hip_runtime.h>

// Ranger_Averager: out = fault ? boxmean3x3_edge_truncated(x) : x
// fault = (x < -2.5f) | (x > 2.5f)
// x shape: [16, 64, 256, 256] fp32 (NCHW). Plane = 256*256 = 65536 elements.
//
// Memory-bound streaming kernel: each thread owns 4 consecutive pixels in a
// row (float4 load/store). Fast path = pure copy. Rare slow path (per-lane
// predicated) computes the edge-truncated 3x3 mean with scalar loads that hit
// L1/L2 (neighbors are being streamed by adjacent threads anyway).

#define RA_LB (-2.5f)
#define RA_UB (2.5f)

__global__ __launch_bounds__(256) void ranger_averager_kernel(
    const float* __restrict__ in, float* __restrict__ out, int total4) {
    const int tid = blockIdx.x * blockDim.x + threadIdx.x;
    if (tid >= total4) return;

    const long pix = (long)tid * 4;  // global element index of first pixel
    const float4 v = *reinterpret_cast<const float4*>(in + pix);

    float r[4] = {v.x, v.y, v.z, v.w};
    bool f[4];
    f[0] = (v.x < RA_LB) | (v.x > RA_UB);
    f[1] = (v.y < RA_LB) | (v.y > RA_UB);
    f[2] = (v.z < RA_LB) | (v.z > RA_UB);
    f[3] = (v.w < RA_LB) | (v.w > RA_UB);

    if (f[0] | f[1] | f[2] | f[3]) {
        // coordinates within the 256x256 plane (4 | 256 so no row crossing)
        const int w = (int)(pix & 255);          // 0,4,...,252
        const int h = (int)((pix >> 8) & 255);   // row in plane
        const long planeBase = pix & ~65535L;    // start of this (n,c) plane
        const int h0 = (h > 0) ? h - 1 : 0;
        const int h1 = (h < 255) ? h + 1 : 255;
        const float nRows = (float)(h1 - h0 + 1);
        const float* __restrict__ p = in + planeBase;

#pragma unroll
        for (int e = 0; e < 4; ++e) {
            if (f[e]) {
                const int ww = w + e;
                const int w0 = (ww > 0) ? ww - 1 : 0;
                const int w1 = (ww < 255) ? ww + 1 : 255;
                float s = 0.0f;
                for (int yy = h0; yy <= h1; ++yy) {
                    const float* __restrict__ row = p + ((long)yy << 8);
                    for (int xx = w0; xx <= w1; ++xx) s += row[xx];
                }
                r[e] = s / (nRows * (float)(w1 - w0 + 1));
            }
        }
    }

    float4 o;
    o.x = r[0]; o.y = r[1]; o.z = r[2]; o.w = r[3];
    *reinterpret_cast<float4*>(out + pix) = o;
}

extern "C" void kernel_launch(void* const* d_in, const int* in_sizes, int n_in,
                              void* d_out, int out_size, void* d_ws, size_t ws_size,
                              hipStream_t stream) {
    const float* x = (const float*)d_in[0];
    float* out = (float*)d_out;
    const int n = in_sizes[0];          // 67,108,864
    const int total4 = n / 4;           // 16,777,216 float4-groups
    const int block = 256;
    const int grid = (total4 + block - 1) / block;
    ranger_averager_kernel<<<grid, block, 0, stream>>>(x, out, total4);
}

// Round 2
// 429.607 us; speedup vs baseline: 1.2315x; 1.2315x over previous
//
#include <hip/hip_runtime.h>

// Ranger_Averager: out = fault ? boxmean3x3_edge_truncated(x) : x
// fault = (x < -2.5f) | (x > 2.5f); x: [16,64,256,256] fp32, plane = 65536.
//
// Streaming float4 copy + rare predicated slow path. Slow path is fully
// unrolled: 3x3 neighborhood via CLAMPED addresses (always in-bounds) and
// validity-mask weights (edge truncation = weight 0, count adjusts), so all
// loads are independent -> one memory round-trip instead of a 9-deep
// dependent chain (R0's latency bottleneck: 1.8 TB/s, VALUBusy 28%).

#define RA_LB (-2.5f)
#define RA_UB (2.5f)

__global__ __launch_bounds__(256) void ranger_averager_kernel(
    const float* __restrict__ in, float* __restrict__ out, int total4) {
    const int tid = blockIdx.x * blockDim.x + threadIdx.x;
    if (tid >= total4) return;

    const long pix = (long)tid * 4;  // first pixel of this thread's group
    const float4 v = *reinterpret_cast<const float4*>(in + pix);

    float vv[4] = {v.x, v.y, v.z, v.w};
    float r[4]  = {v.x, v.y, v.z, v.w};
    bool f[4];
#pragma unroll
    for (int e = 0; e < 4; ++e) f[e] = (vv[e] < RA_LB) | (vv[e] > RA_UB);

    if (__builtin_expect(f[0] | f[1] | f[2] | f[3], 0)) {
        const int w = (int)(pix & 255);          // 0,4,...,252 (4 | 256)
        const int h = (int)((pix >> 8) & 255);   // row in plane
        const float* __restrict__ p = in + (pix & ~65535L);

        const int ym = h - (h > 0);              // clamped row indices
        const int yp = h + (h < 255);
        const float rm = (h > 0)   ? 1.0f : 0.0f;  // row validity weights
        const float rp = (h < 255) ? 1.0f : 0.0f;
        const float* __restrict__ rowm = p + ((long)ym << 8);
        const float* __restrict__ row0 = p + ((long)h  << 8);
        const float* __restrict__ rowp = p + ((long)yp << 8);

#pragma unroll
        for (int e = 0; e < 4; ++e) {
            if (f[e]) {
                const int ww = w + e;
                const int xm = ww - (ww > 0);    // clamped col indices
                const int xp = ww + (ww < 255);
                const float cm = (ww > 0)   ? 1.0f : 0.0f;
                const float cp = (ww < 255) ? 1.0f : 0.0f;

                // 6 independent loads (top+bottom rows); center row mostly
                // comes from the float4 already in registers.
                const float am = rowm[xm], a0 = rowm[ww], ap = rowm[xp];
                const float dm = rowp[xm], d0 = rowp[ww], dp = rowp[xp];
                const float bm = (e == 0) ? row0[xm] : vv[e - 1];
                const float bp = (e == 3) ? row0[xp] : vv[e + 1];

                const float s =
                    rm * (cm * am + a0 + cp * ap) +
                         (cm * bm + vv[e] + cp * bp) +
                    rp * (cm * dm + d0 + cp * dp);
                const float cnt = (1.0f + rm + rp) * (1.0f + cm + cp);
                r[e] = s / cnt;
            }
        }
    }

    float4 o;
    o.x = r[0]; o.y = r[1]; o.z = r[2]; o.w = r[3];
    *reinterpret_cast<float4*>(out + pix) = o;
}

extern "C" void kernel_launch(void* const* d_in, const int* in_sizes, int n_in,
                              void* d_out, int out_size, void* d_ws, size_t ws_size,
                              hipStream_t stream) {
    const float* x = (const float*)d_in[0];
    float* out = (float*)d_out;
    const int n = in_sizes[0];          // 67,108,864
    const int total4 = n / 4;           // 16,777,216 float4 groups
    const int block = 256;
    const int grid = (total4 + block - 1) / block;
    ranger_averager_kernel<<<grid, block, 0, stream>>>(x, out, total4);
}